// Round 1
// 842.053 us; speedup vs baseline: 1.3958x; 1.3958x over previous
//
#include <hip/hip_runtime.h>
#include <math.h>

#define B_ 4
#define H_ 16
#define S_ 1024
#define R_ 512
#define BQ 64
#define BK 32
#define NTHREADS 512
#define NKS 16   // K steps in mm1: 512 / 32

typedef unsigned short u16;
typedef unsigned int   u32;
typedef short bf16x8 __attribute__((ext_vector_type(8)));
typedef float f32x4  __attribute__((ext_vector_type(4)));

__device__ inline u16 f2bf(float x) {
    union { float f; u32 u; } v; v.f = x;
    return (u16)((v.u + 0x7fffu + ((v.u >> 16) & 1u)) >> 16);
}
__device__ inline u32 pack2(float a, float b) {
    return (u32)f2bf(a) | ((u32)f2bf(b) << 16);
}

#define MFMA16(a, b, c) __builtin_amdgcn_mfma_f32_16x16x32_bf16(a, b, c, 0, 0, 0)

// async global->LDS, 16B per lane. LDS dest must be wave-uniform (HW adds lane*16).
__device__ inline void gload16(const void* g, void* l) {
    __builtin_amdgcn_global_load_lds(
        (const __attribute__((address_space(1))) void*)g,
        (__attribute__((address_space(3))) void*)l,
        16, 0, 0);
}

// barrier that does NOT drain vmcnt (keeps global_load_lds prefetch in flight),
// but drains lgkm so LDS writes are visible across waves.
#define RAW_BARRIER() do {                                 \
    asm volatile("s_waitcnt lgkmcnt(0)" ::: "memory");     \
    __builtin_amdgcn_s_barrier();                          \
    asm volatile("" ::: "memory");                         \
} while (0)

// ---------------------------------------------------------------------------
// Prep kernel: ckv f32 -> bf16, two layouts in workspace:
//   ckv_bf [b][k][r]  with 16B chunks XOR-swizzled within each 128B span:
//       byte_pos_in_row(r) = (2r) ^ ((k&7)<<4)
//     so a LINEAR global_load_lds gives a bank-conflict-free LDS layout.
//   ckvT   [b][r][k]  plain (64B LDS rows are naturally conflict-free).
// grid (S/64, R/64, B) x 256
// ---------------------------------------------------------------------------
__global__ __launch_bounds__(256)
void mla_prep_kernel(const float* __restrict__ ckv,
                     u16* __restrict__ ckv_bf,
                     u16* __restrict__ ckvT)
{
    const int tid = threadIdx.x;
    const int k0 = blockIdx.x * 64;
    const int r0 = blockIdx.y * 64;
    const int b  = blockIdx.z;

    __shared__ u16 sT[64][72];   // [r_local][k_local], padded rows

    const float* src = ckv + ((size_t)b * S_ + k0) * R_ + r0;
    u16* obf = ckv_bf + ((size_t)b * S_ + k0) * R_ + r0;

    #pragma unroll
    for (int i = 0; i < 2; ++i) {
        int idx = tid + i * 256;          // 0..511
        int kk  = idx >> 3;               // 0..63 local k row
        int c8  = idx & 7;                // dest 16B chunk within 128B span
        int csrc = c8 ^ (kk & 7);         // source chunk (XOR swizzle)
        const float* p = src + (size_t)kk * R_ + csrc * 8;
        float4 f0 = *(const float4*)p;
        float4 f1 = *(const float4*)(p + 4);
        u32 w0 = pack2(f0.x, f0.y), w1 = pack2(f0.z, f0.w);
        u32 w2 = pack2(f1.x, f1.y), w3 = pack2(f1.z, f1.w);
        u32* dst = (u32*)(obf + (size_t)kk * R_ + c8 * 8);
        dst[0] = w0; dst[1] = w1; dst[2] = w2; dst[3] = w3;
        u16 e[8] = {(u16)w0,(u16)(w0>>16),(u16)w1,(u16)(w1>>16),
                    (u16)w2,(u16)(w2>>16),(u16)w3,(u16)(w3>>16)};
        #pragma unroll
        for (int j = 0; j < 8; ++j) sT[csrc * 8 + j][kk] = e[j];
    }
    __syncthreads();

    u16* obT = ckvT + (size_t)b * R_ * S_;
    #pragma unroll
    for (int i = 0; i < 2; ++i) {
        int idx = tid + i * 256;          // 0..511
        int rr = idx >> 3;                // 0..63 local r row
        int kc = idx & 7;                 // 16B chunk along k
        const u16* s = &sT[rr][kc * 8];
        u32* dd = (u32*)(obT + (size_t)(r0 + rr) * S_ + k0 + kc * 8);
        dd[0] = (u32)s[0] | ((u32)s[1] << 16);
        dd[1] = (u32)s[2] | ((u32)s[3] << 16);
        dd[2] = (u32)s[4] | ((u32)s[5] << 16);
        dd[3] = (u32)s[6] | ((u32)s[7] << 16);
    }
}

// ---------------------------------------------------------------------------
// Main kernel. 8 waves: qg = wv>>1 (4 q-groups x 16 rows), ktg = wv&1 (kt half).
// waves_per_eu(2,2): pin the 256-VGPR tier -> NO scratch spills (aq+acc=128
// persistent; prior build spilled at the 128-VGPR tier: WRITE_SIZE 226MB vs
// 134MB output). LDS 133KB -> 1 block/CU by design.
// ---------------------------------------------------------------------------
__global__ __attribute__((amdgpu_waves_per_eu(2, 2)))
__launch_bounds__(NTHREADS)
void mla_attn_kernel(const float* __restrict__ qn,
                     const float* __restrict__ rope,
                     const int*   __restrict__ mask,
                     const int*   __restrict__ cmaskp,
                     const u16*   __restrict__ ckv_bf,
                     const u16*   __restrict__ ckvT,
                     float*       __restrict__ out)
{
    const int tid  = threadIdx.x;
    const int lane = tid & 63;
    const int wv   = tid >> 6;     // wave 0..7
    const int l15  = lane & 15;
    const int lq   = lane >> 4;    // quad 0..3
    const int qg   = wv >> 1;      // q-group 0..3 (16 rows each)
    const int ktg  = wv & 1;       // kt-half 0..1 (16 cols each)

    // heavy (high-qt, causal) blocks first to shrink the imbalance tail
    const int qt = (int)gridDim.x - 1 - (int)blockIdx.x;
    const int h  = blockIdx.y;
    const int b  = blockIdx.z;
    const int q0 = qt * BQ;

    const int cflag = cmaskp[0];

    // LDS: 2*32KB + 2*32KB + 5KB = 136,192 B (1 block/CU)
    __shared__ __align__(16) u16 sCKV [2][BK][R_];   // swizzled rows, 1024B each
    __shared__ __align__(16) u16 sCKVT[2][R_][BK];   // plain 64B rows
    // sP row (40 u16 = 80B): cols 0..31 = P bf16; f32 @32 = alpha;
    // f32 @34 = exchange slot ktg0; f32 @36 = slot ktg1
    __shared__ __align__(16) u16 sP[BQ][40];

    // ---- Q fragments in registers: wave qg owns rows [qg*16,+16), full K=512
    bf16x8 aq[NKS];
    {
        const float* qrow = qn + ((size_t)((b * H_ + h) * S_ + q0 + qg * 16 + l15)) * R_;
        #pragma unroll
        for (int s = 0; s < NKS; ++s) {
            const float* p = qrow + 32 * s + lq * 8;
            float4 f0 = *(const float4*)p;
            float4 f1 = *(const float4*)(p + 4);
            union { u32 u[4]; bf16x8 v; } cv;
            cv.u[0] = pack2(f0.x, f0.y); cv.u[1] = pack2(f0.z, f0.w);
            cv.u[2] = pack2(f1.x, f1.y); cv.u[3] = pack2(f1.z, f1.w);
            aq[s] = cv.v;
        }
    }

    f32x4 acc[4][4];
    #pragma unroll
    for (int i = 0; i < 4; ++i)
        #pragma unroll
        for (int j = 0; j < 4; ++j)
            acc[i][j] = (f32x4){0.f, 0.f, 0.f, 0.f};

    float m_run[4], l_run[4];
    #pragma unroll
    for (int r = 0; r < 4; ++r) { m_run[r] = -INFINITY; l_run[r] = 0.0f; }

    const u16*   ckvb  = ckv_bf + (size_t)b * S_ * R_;
    const u16*   ckvTb = ckvT   + (size_t)b * R_ * S_;
    const float* ropeb = rope + ((size_t)(b * H_ + h)) * S_ * S_;
    const int*   maskb = mask + b * S_;

    const int nkt = cflag ? ((q0 + BQ) / BK) : (S_ / BK);
    const float SCALE = 0.07216878364870323f;   // 1/sqrt(64+128)
    const int rowg0 = q0 + qg * 16 + 4 * lq;

    float rp[4];
    int   mkv;

    // ---- prologue: async-stage tile 0 (d=0) + rope/mask for tile 0 ----
    {
        char* lA = (char*)&sCKV [0][0][0] + wv * 1024;
        char* lT = (char*)&sCKVT[0][0][0] + wv * 1024;
        #pragma unroll
        for (int rd = 0; rd < 4; ++rd) {
            u32 o = (u32)(rd * 8192 + tid * 16);
            gload16((const char*)ckvb + o, lA + rd * 8192);
            gload16((const char*)ckvTb + (size_t)(o >> 6) * 2048 + (o & 63),
                    lT + rd * 8192);
        }
        #pragma unroll
        for (int reg = 0; reg < 4; ++reg)
            rp[reg] = ropeb[(size_t)(rowg0 + reg) * S_ + ktg * 16 + l15];
        mkv = maskb[ktg * 16 + l15];
    }
    __syncthreads();   // drains vmcnt(0): tile 0 staged

    for (int kt = 0; kt < nkt; ++kt) {
        const int d  = kt & 1;
        const int k0 = kt * BK;
        const bool more = (kt + 1 < nkt);
        float rp_n[4];
        int   mkv_n = 0;

        // ---- issue async stage of tile kt+1 into buffers d^1 (no drain here;
        //      the only vmcnt(0) is the __syncthreads at end of this tile) ----
        if (more) {
            const int k0n = k0 + BK;
            const char* gA = (const char*)ckvb  + (size_t)k0n * 1024;
            const char* gT = (const char*)ckvTb + (size_t)k0n * 2;
            char* lA = (char*)&sCKV [d ^ 1][0][0] + wv * 1024;
            char* lT = (char*)&sCKVT[d ^ 1][0][0] + wv * 1024;
            #pragma unroll
            for (int rd = 0; rd < 4; ++rd) {
                u32 o = (u32)(rd * 8192 + tid * 16);
                gload16(gA + o, lA + rd * 8192);
                gload16(gT + (size_t)(o >> 6) * 2048 + (o & 63), lT + rd * 8192);
            }
            #pragma unroll
            for (int reg = 0; reg < 4; ++reg)
                rp_n[reg] = ropeb[(size_t)(rowg0 + reg) * S_ + k0n + ktg * 16 + l15];
            mkv_n = maskb[k0n + ktg * 16 + l15];
        }

        // ---- phase A: mm1 (swizzled conflict-free B-frag reads), row max ----
        f32x4 sc0 = {0.f,0.f,0.f,0.f}, sc1 = {0.f,0.f,0.f,0.f};
        {
            const char* base = (const char*)&sCKV[d][0][0];
            const u32 rowb = (u32)(ktg * 16 + l15) * 1024;
            const u32 swz  = ((u32)(l15 & 7)) << 4;   // (krow&7)<<4
            #pragma unroll
            for (int s = 0; s < NKS; s += 2) {
                bf16x8 bf0 = *(const bf16x8*)(base + rowb +
                                (((u32)(64 * s)      + (u32)(16 * lq)) ^ swz));
                bf16x8 bf1 = *(const bf16x8*)(base + rowb +
                                (((u32)(64 * s + 64) + (u32)(16 * lq)) ^ swz));
                sc0 = MFMA16(aq[s],     bf0, sc0);
                sc1 = MFMA16(aq[s + 1], bf1, sc1);
            }
        }

        float scf[4], vm[4];
        {
            const int colg = k0 + ktg * 16 + l15;
            #pragma unroll
            for (int reg = 0; reg < 4; ++reg) {
                float v = (sc0[reg] + sc1[reg] + rp[reg]) * SCALE;
                if (mkv) v = -INFINITY;
                if (cflag && colg > rowg0 + reg) v = -INFINITY;
                scf[reg] = v;
                vm[reg]  = v;
            }
            #pragma unroll
            for (int m = 1; m <= 8; m <<= 1)
                #pragma unroll
                for (int reg = 0; reg < 4; ++reg)
                    vm[reg] = fmaxf(vm[reg], __shfl_xor(vm[reg], m));
            if (l15 == 0) {
                #pragma unroll
                for (int reg = 0; reg < 4; ++reg)
                    *(float*)&sP[qg * 16 + 4 * lq + reg][34 + 2 * ktg] = vm[reg];
            }
        }
        RAW_BARRIER();   // bar1: exchange slots visible; prefetch stays in flight

        // ---- phase B: combine kt-halves, finish softmax, write P + alpha ----
        {
            float pv[4], alpha[4], rs[4];
            #pragma unroll
            for (int reg = 0; reg < 4; ++reg) {
                float pm = *(const float*)&sP[qg * 16 + 4 * lq + reg][34 + 2 * (ktg ^ 1)];
                float mn = fmaxf(m_run[reg], fmaxf(vm[reg], pm));
                if (mn == -INFINITY) {
                    alpha[reg] = 1.0f; pv[reg] = 0.0f;
                } else {
                    alpha[reg] = __expf(m_run[reg] - mn);
                    pv[reg]    = __expf(scf[reg] - mn);
                }
                m_run[reg] = mn;
                rs[reg] = pv[reg];
            }
            #pragma unroll
            for (int m = 1; m <= 8; m <<= 1)
                #pragma unroll
                for (int reg = 0; reg < 4; ++reg)
                    rs[reg] += __shfl_xor(rs[reg], m);
            #pragma unroll
            for (int reg = 0; reg < 4; ++reg) {
                l_run[reg] = l_run[reg] * alpha[reg] + rs[reg];
                sP[qg * 16 + 4 * lq + reg][ktg * 16 + l15] = f2bf(pv[reg]);
            }
            if (ktg == 0 && l15 == 0) {
                #pragma unroll
                for (int reg = 0; reg < 4; ++reg)
                    *(float*)&sP[qg * 16 + 4 * lq + reg][32] = alpha[reg];
            }
        }
        RAW_BARRIER();   // bar2: P + alpha visible; prefetch stays in flight

        // ---- phase C: mm2 (O = O*alpha + P . CKV) ----
        {
            float alr[4][4];
            #pragma unroll
            for (int mi = 0; mi < 4; ++mi)
                #pragma unroll
                for (int reg = 0; reg < 4; ++reg)
                    alr[mi][reg] = *(const float*)&sP[mi * 16 + 4 * lq + reg][32];
            #pragma unroll
            for (int mi = 0; mi < 4; ++mi)
                #pragma unroll
                for (int ni = 0; ni < 4; ++ni)
                    #pragma unroll
                    for (int reg = 0; reg < 4; ++reg)
                        acc[mi][ni][reg] *= alr[mi][reg];

            const int kq = lq * 8;
            bf16x8 af[4], bfr[4];
            #pragma unroll
            for (int mi = 0; mi < 4; ++mi)
                af[mi] = *(const bf16x8*)&sP[mi * 16 + l15][kq];
            const char* tbase = (const char*)&sCKVT[d][0][0];
            #pragma unroll
            for (int ni = 0; ni < 4; ++ni)
                bfr[ni] = *(const bf16x8*)(tbase +
                            (u32)(wv * 64 + ni * 16 + l15) * 64 + (u32)(lq * 16));
            #pragma unroll
            for (int mi = 0; mi < 4; ++mi)
                #pragma unroll
                for (int ni = 0; ni < 4; ++ni)
                    acc[mi][ni] = MFMA16(af[mi], bfr[ni], acc[mi][ni]);
        }
        __syncthreads();   // bar3: drains vmcnt(0) -> tile kt+1 staged & visible

        #pragma unroll
        for (int reg = 0; reg < 4; ++reg) rp[reg] = more ? rp_n[reg] : rp[reg];
        mkv = more ? mkv_n : mkv;
    }

    // ---- epilogue: exchange per-row l across kt-half waves, then O / l ----
    if (l15 == 0) {
        #pragma unroll
        for (int reg = 0; reg < 4; ++reg)
            *(float*)&sP[qg * 16 + 4 * lq + reg][34 + 2 * ktg] = l_run[reg];
    }
    __syncthreads();

    float linv[4][4];
    #pragma unroll
    for (int mi = 0; mi < 4; ++mi)
        #pragma unroll
        for (int reg = 0; reg < 4; ++reg) {
            int row = mi * 16 + 4 * lq + reg;
            float lt = *(const float*)&sP[row][34] + *(const float*)&sP[row][36];
            linv[mi][reg] = 1.0f / lt;
        }

    float* ob = out + ((size_t)((b * H_ + h) * S_ + q0)) * R_;
    #pragma unroll
    for (int mi = 0; mi < 4; ++mi)
        #pragma unroll
        for (int ni = 0; ni < 4; ++ni)
            #pragma unroll
            for (int reg = 0; reg < 4; ++reg)
                ob[(size_t)(mi * 16 + 4 * lq + reg) * R_ + wv * 64 + ni * 16 + l15]
                    = acc[mi][ni][reg] * linv[mi][reg];
}

extern "C" void kernel_launch(void* const* d_in, const int* in_sizes, int n_in,
                              void* d_out, int out_size, void* d_ws, size_t ws_size,
                              hipStream_t stream)
{
    (void)in_sizes; (void)n_in; (void)out_size; (void)ws_size;
    const float* qn   = (const float*)d_in[0];
    const float* ckv  = (const float*)d_in[1];
    const float* rope = (const float*)d_in[2];
    const int*   mask = (const int*)d_in[3];
    const int*   cm   = (const int*)d_in[4];
    float* out = (float*)d_out;

    // workspace: ckv_bf (4MB, swizzled [b][k][r]) + ckvT (4MB, [b][r][k]); needs 8MB
    u16* ckv_bf = (u16*)d_ws;
    u16* ckvT   = ckv_bf + (size_t)B_ * S_ * R_;

    hipLaunchKernelGGL(mla_prep_kernel, dim3(S_ / 64, R_ / 64, B_), dim3(256),
                       0, stream, ckv, ckv_bf, ckvT);
    hipLaunchKernelGGL(mla_attn_kernel, dim3(S_ / BQ, H_, B_), dim3(NTHREADS),
                       0, stream, qn, rope, mask, cm, ckv_bf, ckvT, out);
}